// Round 8
// baseline (388.960 us; speedup 1.0000x reference)
//
#include <hip/hip_runtime.h>

#define TS 64
#define NB 256
#define DI 32
#define NH 10
#define IND 42

struct Cx { float r, i; };
__device__ __forceinline__ Cx cmul(Cx a, Cx b){ return { a.r*b.r - a.i*b.i, a.r*b.i + a.i*b.r }; }
__device__ __forceinline__ Cx csel(Cx a, Cx b, int bit){ return { bit ? b.r : a.r, bit ? b.i : a.i }; }

// xor-lane exchange via LDS pipe: ds_swizzle for masks 4,8,16; shfl for 32
template<int MSK>
__device__ __forceinline__ float sx(float v){
  if constexpr (MSK < 32) {
    constexpr int off = (MSK << 10) | 0x1F;   // BitMode: xor=MSK, or=0, and=0x1F
    return __int_as_float(__builtin_amdgcn_ds_swizzle(__float_as_int(v), off));
  } else {
    return __shfl_xor(v, 32);
  }
}

// xor-lane exchange via DPP quad_perm (VALU pipe, no LDS): masks 1,2
// quad_perm[1,0,3,2] = 0xB1 (xor1), quad_perm[2,3,0,1] = 0x4E (xor2)
template<int CTRL>
__device__ __forceinline__ float dppx(float v){
  return __int_as_float(__builtin_amdgcn_update_dpp(
      0, __float_as_int(v), CTRL, 0xF, 0xF, true));
}

__device__ __forceinline__ float sigm(float x){ return 1.f/(1.f + __expf(-x)); }
__device__ __forceinline__ float tanhr(float x){ float e = __expf(2.f*x); return 1.f - 2.f/(e + 1.f); }

// cross-lane layer-2 gate via DPP (wires 4,5 = lane bits 0,1)
template<int CTRL>
__device__ __forceinline__ void xgateDPP(float* sre, float* simg,
                                         float car, float cai, float cbr, float cbi){
  float pr[16], pi[16];
  #pragma unroll
  for (int s = 0; s < 16; s++) pr[s] = dppx<CTRL>(sre[s]);
  #pragma unroll
  for (int s = 0; s < 16; s++) pi[s] = dppx<CTRL>(simg[s]);
  #pragma unroll
  for (int s = 0; s < 16; s++){
    float nr = car*sre[s]  - cai*simg[s] + cbr*pr[s] - cbi*pi[s];
    float ni = car*simg[s] + cai*sre[s]  + cbi*pr[s] + cbr*pi[s];
    sre[s] = nr; simg[s] = ni;
  }
}

// four in-slot single-qubit gates (slot bits 0..3), pure VALU
__device__ __forceinline__ void slotGates(float* sre, float* simg,
                                          const float4* ql, const float4* qh){
  #pragma unroll
  for (int w = 0; w < 4; w++) {
    float4 u0 = ql[w], u1 = qh[w];
    #pragma unroll
    for (int s = 0; s < 16; s++) {
      if (!(s & (1 << w))) {
        int s2i = s | (1 << w);
        float ar = sre[s], ai = simg[s], br = sre[s2i], bi = simg[s2i];
        sre[s]    = u0.x*ar - u0.y*ai + u0.z*br - u0.w*bi;
        simg[s]   = u0.x*ai + u0.y*ar + u0.z*bi + u0.w*br;
        sre[s2i]  = u1.x*ar - u1.y*ai + u1.z*br - u1.w*bi;
        simg[s2i] = u1.x*ai + u1.y*ar + u1.z*bi + u1.w*br;
      }
    }
  }
}

// combined U = RY(t3)*RX(t2)*RZ(t1) -> 8 floats (row0 r/i pairs, row1 r/i pairs)
__device__ __forceinline__ void mkU(float t1, float t2, float t3, float* dst){
  float c1 = __cosf(0.5f*t1), s1 = __sinf(0.5f*t1);
  float c2 = __cosf(0.5f*t2), s2 = __sinf(0.5f*t2);
  float c3 = __cosf(0.5f*t3), s3 = __sinf(0.5f*t3);
  float A00r =  c2*c1, A00i = -c2*s1;
  float A01r =  s2*s1, A01i = -s2*c1;
  float A10r = -s2*s1, A10i = -s2*c1;
  float A11r =  c2*c1, A11i =  c2*s1;
  dst[0] = c3*A00r - s3*A10r; dst[1] = c3*A00i - s3*A10i;
  dst[2] = c3*A01r - s3*A11r; dst[3] = c3*A01i - s3*A11i;
  dst[4] = s3*A00r + c3*A10r; dst[5] = s3*A00i + c3*A10i;
  dst[6] = s3*A01r + c3*A11r; dst[7] = s3*A01i + c3*A11i;
}

// One block per batch element. Wave g (0..3) = circuit g. 1024 amps = 64 lanes x 16 slots.
// Layout L1: slot bits = wires 0-3, lane bits 0..5 = wires 4..9.
// After wave-private LDS transpose (slot bits <-> lane bits 2-5), layout L2:
//   slot bits = wires 6-9; lane bits: 0->w4, 1->w5, 2->w0, 3->w1, 4->w2, 5->w3.
// All 10 layer-2 gates are VALU/DPP; DS ops per step: ~87 (was ~244).
__global__ __launch_bounds__(256, 1)
void qlstm_kernel(const float* __restrict__ xin,
                  const float* __restrict__ qp,
                  const float* __restrict__ Wf, const float* __restrict__ bfp,
                  const float* __restrict__ Wi, const float* __restrict__ bip,
                  const float* __restrict__ Wg, const float* __restrict__ bgp,
                  const float* __restrict__ Wo, const float* __restrict__ bop,
                  float* __restrict__ out)
{
  __shared__ __align__(16) float ltr[4][1024][2];   // 32 KB transpose scratch (per-wave 8 KB)
  __shared__ __align__(16) float lv[4][NH][4];      // per-wave encoded+layer1 2-vectors
  __shared__ float lq[2][4][NH];                    // double-buffered raw E exchange
  __shared__ float lhxw[4][NH];                     // per-wave private h state
  __shared__ __align__(16) float lU2s[NH][8];       // layer-2 matrices (staging)

  const int tid  = threadIdx.x;
  const int b    = blockIdx.x;
  const int g    = tid >> 6;
  const int lane = tid & 63;
  const int hrow = (lane < NH) ? lane : 0;

  // ---- init: register-resident weights + gate matrices ----
  const float* Wsel = (g==0) ? Wf : (g==1) ? Wi : (g==2) ? Wg : Wo;
  const float* bsel = (g==0) ? bfp : (g==1) ? bip : (g==2) ? bgp : bop;
  float wreg[IND];
  #pragma unroll
  for (int k = 0; k < IND; k++) wreg[k] = Wsel[hrow*IND + k];
  const float breg = bsel[hrow];

  float U1[8];   // layer-1 combined matrix for wire == hrow
  mkU(qp[hrow*3+0], qp[hrow*3+1], qp[hrow*3+2], U1);

  if (tid < NH) {
    float u[8];
    mkU(qp[30 + tid*3 + 0], qp[30 + tid*3 + 1], qp[30 + tid*3 + 2], u);
    #pragma unroll
    for (int i = 0; i < 8; i++) lU2s[tid][i] = u[i];
  }
  if (lane < NH) lhxw[g][lane] = 0.f;
  __syncthreads();

  // layer-2 matrices -> registers
  float4 gql[4], gqh[4];      // wires 0..3 (L1 in-slot)
  float4 gql2[4], gqh2[4];    // wires 6..9 (L2 in-slot)
  #pragma unroll
  for (int w = 0; w < 4; w++) {
    gql[w]  = *reinterpret_cast<const float4*>(&lU2s[w][0]);
    gqh[w]  = *reinterpret_cast<const float4*>(&lU2s[w][4]);
    gql2[w] = *reinterpret_cast<const float4*>(&lU2s[6+w][0]);
    gqh2[w] = *reinterpret_cast<const float4*>(&lU2s[6+w][4]);
  }
  float c4[4], c5[4];         // pre-selected DPP-gate coefficients (wires 4,5)
  #pragma unroll
  for (int j = 0; j < 2; j++) {
    float4 lo = *reinterpret_cast<const float4*>(&lU2s[4+j][0]);
    float4 hi = *reinterpret_cast<const float4*>(&lU2s[4+j][4]);
    bool m = (lane >> j) & 1;
    float* c = j ? c5 : c4;
    c[0] = m ? hi.z : lo.x;  c[1] = m ? hi.w : lo.y;   // own-amp coef
    c[2] = m ? hi.x : lo.z;  c[3] = m ? hi.y : lo.w;   // partner coef
  }

  const int l0 = lane&1, l1 = (lane>>1)&1, l2 = (lane>>2)&1,
            l3 = (lane>>3)&1, l4 = (lane>>4)&1, l5 = (lane>>5)&1;

  // ---- transpose addresses (loop-invariant, +lane bank swizzle) ----
  unsigned wa[16], ra[16];
  {
    const unsigned base = (unsigned)g * 8192u;
    #pragma unroll
    for (int s = 0; s < 16; s++)
      wa[s] = base + (unsigned)lane*128u + (unsigned)(((s + lane) & 15) << 3);
    #pragma unroll
    for (int s2 = 0; s2 < 16; s2++) {
      int lo = (lane & 3) | (s2 << 2);   // writer lane of this amp
      int so = lane >> 2;                // writer slot of this amp
      ra[s2] = base + (unsigned)lo*128u + (unsigned)(((so + lo) & 15) << 3);
    }
  }
  char* lp = (char*)&ltr[0][0][0];

  // ---- x software pipeline: xf holds x[t+1]; wxc = W.x for current t ----
  const float* xb = xin + (size_t)b*DI;
  float4 xf[8];
  #pragma unroll
  for (int r = 0; r < 8; r++) xf[r] = *reinterpret_cast<const float4*>(xb + r*4);
  float wxc = 0.f;
  #pragma unroll
  for (int r = 0; r < 8; r++) {
    wxc = fmaf(wreg[4*r+0], xf[r].x, wxc);
    wxc = fmaf(wreg[4*r+1], xf[r].y, wxc);
    wxc = fmaf(wreg[4*r+2], xf[r].z, wxc);
    wxc = fmaf(wreg[4*r+3], xf[r].w, wxc);
  }
  #pragma unroll
  for (int r = 0; r < 8; r++)
    xf[r] = *reinterpret_cast<const float4*>(xb + (size_t)1*NB*DI + r*4);

  float cstate = 0.f, hval = 0.f;

  for (int t = 0; t < TS; t++) {
    const int tb = t & 1;
    // ---- (a) pre-activation: registers + 10 LDS broadcast reads ----
    float pre = wxc + breg;
    #pragma unroll
    for (int j = 0; j < NH; j++) pre = fmaf(wreg[DI+j], lhxw[g][j], pre);
    float sh, ch;
    __sincosf(0.5f*pre, &sh, &ch);
    if (lane < NH) {
      *reinterpret_cast<float4*>(&lv[g][lane][0]) =
        make_float4(U1[0]*ch + U1[2]*sh, U1[1]*ch + U1[3]*sh,
                    U1[4]*ch + U1[6]*sh, U1[5]*ch + U1[7]*sh);
    }

    // ---- pipeline advance: Wx for t+1, load x for t+2 ----
    float wxn = 0.f;
    #pragma unroll
    for (int r = 0; r < 8; r++) {
      wxn = fmaf(wreg[4*r+0], xf[r].x, wxn);
      wxn = fmaf(wreg[4*r+1], xf[r].y, wxn);
      wxn = fmaf(wreg[4*r+2], xf[r].z, wxn);
      wxn = fmaf(wreg[4*r+3], xf[r].w, wxn);
    }
    {
      int tn = (t + 2 < TS) ? t + 2 : 0;
      #pragma unroll
      for (int r = 0; r < 8; r++)
        xf[r] = *reinterpret_cast<const float4*>(xb + (size_t)tn*NB*DI + r*4);
    }

    // ---- (b) fetch per-wire 2-vectors ----
    Cx vz[NH], vo[NH];
    #pragma unroll
    for (int w = 0; w < NH; w++) {
      float4 tv = *reinterpret_cast<const float4*>(&lv[g][w][0]);
      vz[w] = { tv.x, tv.y };  vo[w] = { tv.z, tv.w };
    }

    // ---- (c) build state = ring1( product(v) ), layout L1 ----
    Cx f5 = csel(vz[5], vo[5], l0^l1);
    Cx f6 = csel(vz[6], vo[6], l1^l2);
    Cx f7 = csel(vz[7], vo[7], l2^l3);
    Cx f8 = csel(vz[8], vo[8], l3^l4);
    Cx f9 = csel(vz[9], vo[9], l4^l5);
    Cx P  = cmul(cmul(f5, f6), cmul(f7, cmul(f8, f9)));
    Cx a4[2]; a4[0] = csel(vz[4], vo[4], l0); a4[1] = csel(vo[4], vz[4], l0);
    Cx u0s[2]; u0s[0] = csel(vz[0], vo[0], l5); u0s[1] = csel(vo[0], vz[0], l5);
    Cx u1s[2]; u1s[0] = csel(vz[1], vo[1], l5); u1s[1] = csel(vo[1], vz[1], l5);
    Cx A[2];  A[0] = cmul(P, a4[0]);  A[1] = cmul(P, a4[1]);
    Cx C[4];
    #pragma unroll
    for (int s1b = 0; s1b < 2; s1b++)
      #pragma unroll
      for (int s0b = 0; s0b < 2; s0b++)
        C[s1b*2+s0b] = cmul(u1s[s0b^s1b], u0s[s0b]);
    Cx AB[8];
    #pragma unroll
    for (int s3b = 0; s3b < 2; s3b++)
      #pragma unroll
      for (int s2b = 0; s2b < 2; s2b++)
        #pragma unroll
        for (int s1b = 0; s1b < 2; s1b++) {
          Cx m23 = cmul((s2b^s3b) ? vo[3] : vz[3], (s1b^s2b) ? vo[2] : vz[2]);
          AB[s3b*4+s2b*2+s1b] = cmul(A[s3b], m23);
        }
    float sre[16], simg[16];
    #pragma unroll
    for (int s = 0; s < 16; s++) {
      int s0b = s&1, s1b = (s>>1)&1, s2b = (s>>2)&1, s3b = (s>>3)&1;
      Cx amp = cmul(AB[s3b*4+s2b*2+s1b], C[s1b*2+s0b]);
      sre[s] = amp.r; simg[s] = amp.i;
    }

    // ---- (d1) gates wires 0-3 (in-slot, L1) + wires 4,5 (DPP) ----
    slotGates(sre, simg, gql, gqh);
    xgateDPP<0xB1>(sre, simg, c4[0], c4[1], c4[2], c4[3]);   // wire 4, xor1
    xgateDPP<0x4E>(sre, simg, c5[0], c5[1], c5[2], c5[3]);   // wire 5, xor2

    // ---- (d2) wave-private transpose L1 -> L2 (slot bits <-> lane bits 2-5) ----
    #pragma unroll
    for (int s = 0; s < 16; s++)
      *reinterpret_cast<float2*>(lp + wa[s]) = make_float2(sre[s], simg[s]);
    #pragma unroll
    for (int s2 = 0; s2 < 16; s2++) {
      float2 v = *reinterpret_cast<const float2*>(lp + ra[s2]);
      sre[s2] = v.x; simg[s2] = v.y;
    }

    // ---- (d3) gates wires 6-9 (in-slot, L2) ----
    slotGates(sre, simg, gql2, gqh2);

    // ---- (e) probabilities + Walsh reductions (L2 masks) ----
    float p[16];
    #pragma unroll
    for (int s = 0; s < 16; s++) p[s] = sre[s]*sre[s] + simg[s]*simg[s];
    #pragma unroll
    for (int bit = 1; bit < 16; bit <<= 1) {   // in-slot WHT over wires 6-9
      #pragma unroll
      for (int s = 0; s < 16; s++) {
        if (!(s & bit)) {
          float aa = p[s], bb = p[s|bit];
          p[s] = aa + bb; p[s|bit] = aa - bb;
        }
      }
    }
    // lane-WHT of 5 slot-coefficients in lock-step (stages 1,2 via DPP)
    float a0 = p[0], a1 = p[1], a3 = p[3], a7 = p[7], a15 = p[15];
    {
      float t0,t1,t3,t7,t15; bool m;
      t0=dppx<0xB1>(a0); t1=dppx<0xB1>(a1); t3=dppx<0xB1>(a3); t7=dppx<0xB1>(a7); t15=dppx<0xB1>(a15);
      m = l0;  a0=m?t0-a0:a0+t0; a1=m?t1-a1:a1+t1; a3=m?t3-a3:a3+t3; a7=m?t7-a7:a7+t7; a15=m?t15-a15:a15+t15;
      t0=dppx<0x4E>(a0); t1=dppx<0x4E>(a1); t3=dppx<0x4E>(a3); t7=dppx<0x4E>(a7); t15=dppx<0x4E>(a15);
      m = l1;  a0=m?t0-a0:a0+t0; a1=m?t1-a1:a1+t1; a3=m?t3-a3:a3+t3; a7=m?t7-a7:a7+t7; a15=m?t15-a15:a15+t15;
      t0=sx<4>(a0); t1=sx<4>(a1); t3=sx<4>(a3); t7=sx<4>(a7); t15=sx<4>(a15);
      m = l2;  a0=m?t0-a0:a0+t0; a1=m?t1-a1:a1+t1; a3=m?t3-a3:a3+t3; a7=m?t7-a7:a7+t7; a15=m?t15-a15:a15+t15;
      t0=sx<8>(a0); t1=sx<8>(a1); t3=sx<8>(a3); t7=sx<8>(a7); t15=sx<8>(a15);
      m = l3;  a0=m?t0-a0:a0+t0; a1=m?t1-a1:a1+t1; a3=m?t3-a3:a3+t3; a7=m?t7-a7:a7+t7; a15=m?t15-a15:a15+t15;
      t0=sx<16>(a0); t1=sx<16>(a1); t3=sx<16>(a3); t7=sx<16>(a7); t15=sx<16>(a15);
      m = l4;  a0=m?t0-a0:a0+t0; a1=m?t1-a1:a1+t1; a3=m?t3-a3:a3+t3; a7=m?t7-a7:a7+t7; a15=m?t15-a15:a15+t15;
      t0=sx<32>(a0); t1=sx<32>(a1); t3=sx<32>(a3); t7=sx<32>(a7); t15=sx<32>(a15);
      m = l5;  a0=m?t0-a0:a0+t0; a1=m?t1-a1:a1+t1; a3=m?t3-a3:a3+t3; a7=m?t7-a7:a7+t7; a15=m?t15-a15:a15+t15;
    }
    // L2 pick map: E1..E5 = a0 @ lanes 12,28,60,61,63 ; E6..E9 = a1,a3,a7,a15 @ 63 ; E0 = a15 @ 59
    if      (lane == 12) lq[tb][g][1] = a0;
    else if (lane == 28) lq[tb][g][2] = a0;
    else if (lane == 60) lq[tb][g][3] = a0;
    else if (lane == 61) lq[tb][g][4] = a0;
    else if (lane == 59) lq[tb][g][0] = a15;
    else if (lane == 63) { lq[tb][g][5] = a0; lq[tb][g][6] = a1; lq[tb][g][7] = a3;
                           lq[tb][g][8] = a7; lq[tb][g][9] = a15; }
    __syncthreads();   // the one barrier: raw-E exchange

    // ---- (f) activations + LSTM cell (lanes 0..9, per wave redundantly) ----
    if (lane < NH) {
      float fv = sigm (lq[tb][0][lane]);
      float iv = sigm (lq[tb][1][lane]);
      float gv = tanhr(lq[tb][2][lane]);
      float ov = sigm (lq[tb][3][lane]);
      cstate = fv*cstate + iv*gv;
      hval = ov*tanhr(cstate);
      lhxw[g][lane] = hval;
      if (g == 0) out[(size_t)t*(NB*NH) + b*NH + lane] = hval;
    }
    wxc = wxn;
  }

  if (g == 0 && lane < NH) {
    out[(size_t)TS*NB*NH + b*NH + lane]          = hval;
    out[(size_t)TS*NB*NH + NB*NH + b*NH + lane]  = cstate;
  }
}

extern "C" void kernel_launch(void* const* d_in, const int* in_sizes, int n_in,
                              void* d_out, int out_size, void* d_ws, size_t ws_size,
                              hipStream_t stream) {
  (void)in_sizes; (void)n_in; (void)d_ws; (void)ws_size; (void)out_size;
  qlstm_kernel<<<dim3(NB), dim3(256), 0, stream>>>(
      (const float*)d_in[0], (const float*)d_in[1],
      (const float*)d_in[2], (const float*)d_in[3],
      (const float*)d_in[4], (const float*)d_in[5],
      (const float*)d_in[6], (const float*)d_in[7],
      (const float*)d_in[8], (const float*)d_in[9],
      (float*)d_out);
}

// Round 9
// 182.114 us; speedup vs baseline: 2.1358x; 2.1358x over previous
//
#include <hip/hip_runtime.h>

#define TS 64
#define NB 256
#define DI 32
#define NH 10
#define IND 42

// DPP quad_perm xor-exchange: 0xB1 = xor1, 0x4E = xor2 (VALU pipe)
template<int CTRL>
__device__ __forceinline__ float dppx(float v){
  return __int_as_float(__builtin_amdgcn_update_dpp(
      0, __float_as_int(v), CTRL, 0xF, 0xF, true));
}

__device__ __forceinline__ float sigm(float x){ return 1.f/(1.f + __expf(-x)); }
__device__ __forceinline__ float tanhr(float x){ float e = __expf(2.f*x); return 1.f - 2.f/(e + 1.f); }

// combined U = RY(t3)*RX(t2)*RZ(t1) -> 8 floats (row0 r/i pairs, row1 r/i pairs)
__device__ __forceinline__ void mkU(float t1, float t2, float t3, float* dst){
  float c1 = __cosf(0.5f*t1), s1 = __sinf(0.5f*t1);
  float c2 = __cosf(0.5f*t2), s2 = __sinf(0.5f*t2);
  float c3 = __cosf(0.5f*t3), s3 = __sinf(0.5f*t3);
  float A00r =  c2*c1, A00i = -c2*s1;
  float A01r =  s2*s1, A01i = -s2*c1;
  float A10r = -s2*s1, A10i = -s2*c1;
  float A11r =  c2*c1, A11i =  c2*s1;
  dst[0] = c3*A00r - s3*A10r; dst[1] = c3*A00i - s3*A10i;
  dst[2] = c3*A01r - s3*A11r; dst[3] = c3*A01i - s3*A11i;
  dst[4] = s3*A00r + c3*A10r; dst[5] = s3*A00i + c3*A10i;
  dst[6] = s3*A01r + c3*A11r; dst[7] = s3*A01i + c3*A11i;
}

// One block per batch element. Wave g (0..3) = circuit g.
// Heisenberg transfer-matrix: E_h = Tr(T_0 T_1 ... T_9), T = 4x4 over (k,k') pairs.
// lane = h*4 + sigma: h = mask index (0..9 used), sigma = boundary (k9,k9').
// Per-wire op = 2-bit XOR-conv (WHT -> pointwise Vhat -> invWHT) -> pointwise C,
// where C = B_w (w in mask) or delta (w not in mask); all register-resident.
__global__ __launch_bounds__(256, 1)
void qlstm_kernel(const float* __restrict__ xin,
                  const float* __restrict__ qp,
                  const float* __restrict__ Wf, const float* __restrict__ bfp,
                  const float* __restrict__ Wi, const float* __restrict__ bip,
                  const float* __restrict__ Wg, const float* __restrict__ bgp,
                  const float* __restrict__ Wo, const float* __restrict__ bop,
                  float* __restrict__ out)
{
  __shared__ __align__(16) float lVh[4][NH][4];   // per-wave per-wire conv data
  __shared__ __align__(16) float lBw[4][NH][4];   // B_w = U2^dag Z U2 (B00,B11,B01r,B01i)
  __shared__ float lq[2][4][NH];                  // double-buffered raw E exchange
  __shared__ float lhxw[4][NH];                   // per-wave private h state

  const int tid  = threadIdx.x;
  const int b    = blockIdx.x;
  const int g    = tid >> 6;
  const int lane = tid & 63;
  const int hq   = lane >> 2;        // mask index (valid < 10)
  const int sg_  = lane & 3;         // boundary sigma = k9 + 2*k9'
  const int hrow = (lane < NH) ? lane : 0;

  // ---- init: register-resident weights, layer-1 U, layer-2 B ----
  const float* Wsel = (g==0) ? Wf : (g==1) ? Wi : (g==2) ? Wg : Wo;
  const float* bsel = (g==0) ? bfp : (g==1) ? bip : (g==2) ? bgp : bop;
  float wreg[IND];
  #pragma unroll
  for (int k = 0; k < IND; k++) wreg[k] = Wsel[hrow*IND + k];
  const float breg = bsel[hrow];

  float U1[8];
  mkU(qp[hrow*3+0], qp[hrow*3+1], qp[hrow*3+2], U1);

  if (lane < NH) {
    float u[8];
    mkU(qp[30 + lane*3 + 0], qp[30 + lane*3 + 1], qp[30 + lane*3 + 2], u);
    // B[k,k'] = sum_j (-1)^j U[j,k] conj(U[j,k'])
    float B00 = u[0]*u[0]+u[1]*u[1] - (u[4]*u[4]+u[5]*u[5]);
    float B11 = u[2]*u[2]+u[3]*u[3] - (u[6]*u[6]+u[7]*u[7]);
    float B01r= u[0]*u[2]+u[1]*u[3] - (u[4]*u[6]+u[5]*u[7]);
    float B01i= u[1]*u[2]-u[0]*u[3] - (u[5]*u[6]-u[4]*u[7]);
    *reinterpret_cast<float4*>(&lBw[g][lane][0]) = make_float4(B00,B11,B01r,B01i);
    lhxw[g][lane] = 0.f;
  }
  __syncthreads();

  // per-lane pointwise-C constants for wires 1..9 (B_w if w in M_h, delta else)
  float C00[9], C11[9], Cr[9], Ci[9];
  #pragma unroll
  for (int w = 1; w <= 9; w++) {
    float4 bb = *reinterpret_cast<const float4*>(&lBw[g][w][0]);
    bool inM = (hq == 0) || (w <= hq);       // M_0={1..9}, M_h={0..h}
    C00[w-1] = inM ? bb.x : 1.f;
    C11[w-1] = inM ? bb.y : 1.f;
    Cr[w-1]  = inM ? bb.z : 0.f;
    Ci[w-1]  = inM ? bb.w : 0.f;
  }
  // wire-0 kernel, boundary-shifted: K_i = B0e[i ^ sigma] (delta-based for h==0)
  float Kr[4], Ki[4];
  {
    float4 b0 = *reinterpret_cast<const float4*>(&lBw[g][0][0]);
    float er[4] = { b0.x, b0.z, b0.z, b0.y };   // entries indexed k+2k'
    float ei[4] = { 0.f, -b0.w, b0.w, 0.f };
    if (hq == 0) { er[0]=1.f; er[1]=0.f; er[2]=0.f; er[3]=1.f; ei[1]=0.f; ei[2]=0.f; }
    #pragma unroll
    for (int i = 0; i < 4; i++) { Kr[i] = er[i ^ sg_]; Ki[i] = ei[i ^ sg_]; }
  }

  // ---- x software pipeline (R7): xf holds x[t+1]; wxc = W.x for current t ----
  const float* xb = xin + (size_t)b*DI;
  float4 xf[8];
  #pragma unroll
  for (int r = 0; r < 8; r++) xf[r] = *reinterpret_cast<const float4*>(xb + r*4);
  float wxc = 0.f;
  #pragma unroll
  for (int r = 0; r < 8; r++) {
    wxc = fmaf(wreg[4*r+0], xf[r].x, wxc);
    wxc = fmaf(wreg[4*r+1], xf[r].y, wxc);
    wxc = fmaf(wreg[4*r+2], xf[r].z, wxc);
    wxc = fmaf(wreg[4*r+3], xf[r].w, wxc);
  }
  #pragma unroll
  for (int r = 0; r < 8; r++)
    xf[r] = *reinterpret_cast<const float4*>(xb + (size_t)1*NB*DI + r*4);

  float cstate = 0.f, hval = 0.f;

  for (int t = 0; t < TS; t++) {
    const int tb = t & 1;
    // ---- (a) pre-activation + v build + conv-data write (lanes 0..9) ----
    float pre = wxc + breg;
    #pragma unroll
    for (int j = 0; j < NH; j++) pre = fmaf(wreg[DI+j], lhxw[g][j], pre);
    float sh, ch;
    __sincosf(0.5f*pre, &sh, &ch);
    float v0r = U1[0]*ch + U1[2]*sh, v0i = U1[1]*ch + U1[3]*sh;
    float v1r = U1[4]*ch + U1[6]*sh, v1i = U1[5]*ch + U1[7]*sh;
    if (lane < NH) {
      // wire 0 stores plain products; wires 1-9 store WHT'd (V0,V1)/2 products
      float A0r, A0i, A1r, A1i;
      if (lane == 0) { A0r=v0r; A0i=v0i; A1r=v1r; A1i=v1i; }
      else { A0r=0.5f*(v0r+v1r); A0i=0.5f*(v0i+v1i);
             A1r=0.5f*(v0r-v1r); A1i=0.5f*(v0i-v1i); }
      float n0  = A0r*A0r + A0i*A0i;
      float n1  = A1r*A1r + A1i*A1i;
      float e1r = A1r*A0r + A1i*A0i;
      float e1i = A1i*A0r - A1r*A0i;
      *reinterpret_cast<float4*>(&lVh[g][lane][0]) = make_float4(n0, n1, e1r, e1i);
    }

    // ---- pipeline advance: Wx for t+1, load x for t+2 ----
    float wxn = 0.f;
    #pragma unroll
    for (int r = 0; r < 8; r++) {
      wxn = fmaf(wreg[4*r+0], xf[r].x, wxn);
      wxn = fmaf(wreg[4*r+1], xf[r].y, wxn);
      wxn = fmaf(wreg[4*r+2], xf[r].z, wxn);
      wxn = fmaf(wreg[4*r+3], xf[r].w, wxn);
    }
    {
      int tn = (t + 2 < TS) ? t + 2 : 0;
      #pragma unroll
      for (int r = 0; r < 8; r++)
        xf[r] = *reinterpret_cast<const float4*>(xb + (size_t)tn*NB*DI + r*4);
    }

    // ---- (b) broadcast-read all wires' conv data (wave-private LDS) ----
    float4 vh[NH];
    #pragma unroll
    for (int w = 0; w < NH; w++)
      vh[w] = *reinterpret_cast<const float4*>(&lVh[g][w][0]);

    // ---- (c) transfer chain: r = (prod0 . K), then wires 1..9 ----
    float r0r = vh[0].x*Kr[0],               r0i = vh[0].x*Ki[0];
    float r3r = vh[0].y*Kr[3],               r3i = vh[0].y*Ki[3];
    float r1r = vh[0].z*Kr[1] - vh[0].w*Ki[1], r1i = vh[0].z*Ki[1] + vh[0].w*Kr[1];
    float r2r = vh[0].z*Kr[2] + vh[0].w*Ki[2], r2i = vh[0].z*Ki[2] - vh[0].w*Kr[2];

    #pragma unroll
    for (int w = 1; w <= 9; w++) {
      // 2-bit WHT (index i = b + 2b')
      float ar = r0r + r1r, ai = r0i + r1i;
      float br = r0r - r1r, bi = r0i - r1i;
      float cr2 = r2r + r3r, ci2 = r2i + r3i;
      float dr = r2r - r3r, di = r2i - r3i;
      float u0r = ar + cr2, u0i = ai + ci2;
      float u2r = ar - cr2, u2i = ai - ci2;
      float u1r = br + dr,  u1i = bi + di;
      float u3r = br - dr,  u3i = bi - di;
      // pointwise Vhat: diag entries real (|V0|^2,|V1|^2), off-diag e1
      float4 V = vh[w];
      float m0r = u0r*V.x, m0i = u0i*V.x;
      float m3r = u3r*V.y, m3i = u3i*V.y;
      float m1r = u1r*V.z - u1i*V.w, m1i = u1r*V.w + u1i*V.z;   // * e1
      float m2r = u2r*V.z + u2i*V.w, m2i = u2i*V.z - u2r*V.w;   // * conj(e1)
      // inverse WHT (scale folded into Vhat)
      float p0r = m0r + m1r, p0i = m0i + m1i;
      float p1r = m0r - m1r, p1i = m0i - m1i;
      float p2r = m2r + m3r, p2i = m2i + m3i;
      float p3r = m2r - m3r, p3i = m2i - m3i;
      float y0r = p0r + p2r, y0i = p0i + p2i;
      float y2r = p0r - p2r, y2i = p0i - p2i;
      float y1r = p1r + p3r, y1i = p1i + p3i;
      float y3r = p1r - p3r, y3i = p1i - p3i;
      // pointwise C (Hermitian; delta for w not in mask zeroes off-diags)
      float c0 = C00[w-1], c3 = C11[w-1], ccr = Cr[w-1], cci = Ci[w-1];
      r0r = y0r*c0;  r0i = y0i*c0;
      r3r = y3r*c3;  r3i = y3i*c3;
      r1r = y1r*ccr + y1i*cci;  r1i = y1i*ccr - y1r*cci;   // * conj(B01)
      r2r = y2r*ccr - y2i*cci;  r2i = y2i*ccr + y2r*cci;   // * B01
    }

    // ---- (d) trace: pick entry sigma (real part), quad-sum over sigma ----
    float t0 = (lane & 1) ? r1r : r0r;
    float t1 = (lane & 1) ? r3r : r2r;
    float Ee = (lane & 2) ? t1 : t0;
    Ee += dppx<0xB1>(Ee);
    Ee += dppx<0x4E>(Ee);
    if ((lane & 3) == 0 && hq < NH) lq[tb][g][hq] = Ee;
    __syncthreads();   // the one barrier: raw-E exchange

    // ---- (f) activations + LSTM cell (lanes 0..9, per wave redundantly) ----
    if (lane < NH) {
      float fv = sigm (lq[tb][0][lane]);
      float iv = sigm (lq[tb][1][lane]);
      float gv = tanhr(lq[tb][2][lane]);
      float ov = sigm (lq[tb][3][lane]);
      cstate = fv*cstate + iv*gv;
      hval = ov*tanhr(cstate);
      lhxw[g][lane] = hval;
      if (g == 0) out[(size_t)t*(NB*NH) + b*NH + lane] = hval;
    }
    wxc = wxn;
  }

  if (g == 0 && lane < NH) {
    out[(size_t)TS*NB*NH + b*NH + lane]          = hval;
    out[(size_t)TS*NB*NH + NB*NH + b*NH + lane]  = cstate;
  }
}

extern "C" void kernel_launch(void* const* d_in, const int* in_sizes, int n_in,
                              void* d_out, int out_size, void* d_ws, size_t ws_size,
                              hipStream_t stream) {
  (void)in_sizes; (void)n_in; (void)d_ws; (void)ws_size; (void)out_size;
  qlstm_kernel<<<dim3(NB), dim3(256), 0, stream>>>(
      (const float*)d_in[0], (const float*)d_in[1],
      (const float*)d_in[2], (const float*)d_in[3],
      (const float*)d_in[4], (const float*)d_in[5],
      (const float*)d_in[6], (const float*)d_in[7],
      (const float*)d_in[8], (const float*)d_in[9],
      (float*)d_out);
}